// Round 7
// baseline (1467.144 us; speedup 1.0000x reference)
//
#include <hip/hip_runtime.h>

#define S    8192
#define Dm   4096
#define E    64
#define CAP  128
#define CCH  32          // split-K chunks
#define KC   (Dm/CCH)    // 128 k per chunk
#define KSUB 16          // k sub-tile staged in LDS
#define XSTR 260         // xs row stride: 2-way store conflicts only (free)
#define WSTR 68          // ws row stride: 2-way store conflicts only (free)

#define CW_OFF 1
#define DM_OFF (1 + (size_t)S*E*CAP)
#define EC_OFF (1 + 2*(size_t)S*E*CAP)
// exact output footprint in BYTES (out_size arg is in floats — verified r0==r1)
#define OUT_BYTES ((1 + 2*(size_t)S*E*CAP + E) * sizeof(float))
#define K1B_BLOCKS 512                           // 16 tokens per block, 4 per wave

// ATTRIBUTION ROUND 2: k1 measured at 59us (r6). Now amplify k1b and k2 10x.
// decode: k1b_base = k1b_row_dur/10, k2_base = k2_row_dur/10;
// fixed_overhead = 713 - 341(poison) - 85(memset) - 59(k1) - k1b - k2.
#define K1B_REPS 10
#define K2_REPS  10

// ---------------- K1: register-tiled partial GEMM (round-4 form, 1x) --------
__global__ __launch_bounds__(256)
void k1_partial(const float* __restrict__ x, const float* __restrict__ wg,
                float* __restrict__ part) {
    __shared__ float xs[KSUB][XSTR];   // [k][token]
    __shared__ float wsh[KSUB][WSTR];  // [k][e]
    const int tb  = blockIdx.x >> 5;   // 0..31 token block (256 tokens)
    const int c   = blockIdx.x & 31;   // 0..31 k chunk (128 k)
    const int tid = threadIdx.x;
    const int tt  = tid & 31;          // token group
    const int ee  = tid >> 5;          // expert group (8 experts)
    const int k0  = c * KC;

    float acc[64];
    #pragma unroll
    for (int i = 0; i < 64; i++) acc[i] = 0.f;

    const int xr = tid >> 2;           // 0..63 token row base
    const int xc = tid & 3;            // float4 col within 16 k
    const int we = tid >> 2;           // 0..63 expert (W staging)
    const int wk = (tid & 3) * 4;      // k quad (W staging)

    for (int su = 0; su < KC / KSUB; su++) {
        const int ks0 = k0 + su * KSUB;
        #pragma unroll
        for (int i = 0; i < 4; i++) {
            const int row = i * 64 + xr;
            const float4 v = *(const float4*)(x + (size_t)(tb*256 + row) * Dm + ks0 + xc*4);
            xs[xc*4+0][row] = v.x;
            xs[xc*4+1][row] = v.y;
            xs[xc*4+2][row] = v.z;
            xs[xc*4+3][row] = v.w;
        }
        {
            const float4 v = *(const float4*)(wg + (size_t)we * Dm + ks0 + wk);
            wsh[wk+0][we] = v.x; wsh[wk+1][we] = v.y;
            wsh[wk+2][we] = v.z; wsh[wk+3][we] = v.w;
        }
        __syncthreads();
        #pragma unroll 8
        for (int kk = 0; kk < KSUB; kk++) {
            const float4 a0 = *(const float4*)&xs[kk][tt*4];
            const float4 a1 = *(const float4*)&xs[kk][128 + tt*4];
            const float4 w0 = *(const float4*)&wsh[kk][ee*8];
            const float4 w1 = *(const float4*)&wsh[kk][ee*8+4];
            const float av[8] = {a0.x,a0.y,a0.z,a0.w,a1.x,a1.y,a1.z,a1.w};
            const float wv[8] = {w0.x,w0.y,w0.z,w0.w,w1.x,w1.y,w1.z,w1.w};
            #pragma unroll
            for (int t = 0; t < 8; t++)
                #pragma unroll
                for (int e = 0; e < 8; e++)
                    acc[t*8+e] = fmaf(av[t], wv[e], acc[t*8+e]);
        }
        __syncthreads();
    }
    #pragma unroll
    for (int t = 0; t < 8; t++) {
        const int token = (t < 4) ? (tt*4 + t) : (128 + tt*4 + (t - 4));
        float* dst = part + ((size_t)c * S + tb*256 + token) * E + ee*8;
        *(float4*)(dst)     = make_float4(acc[t*8+0], acc[t*8+1], acc[t*8+2], acc[t*8+3]);
        *(float4*)(dst + 4) = make_float4(acc[t*8+4], acc[t*8+5], acc[t*8+6], acc[t*8+7]);
    }
}

// ---------------- K1b: reduce partials, softmax, argmax — AMPLIFIED 10x -----
__global__ __launch_bounds__(256, 1)
void k1b_softmax(const float* __restrict__ part, float* __restrict__ gate_val,
                 int* __restrict__ idx1, int* __restrict__ counts,
                 float* __restrict__ me_part) {
    const int tid = threadIdx.x, wv = tid >> 6, ln = tid & 63;
    __shared__ float gs[4][64];
    for (int rep = 0; rep < K1B_REPS; rep++) {
        asm volatile("" ::: "memory");   // no cross-rep elimination
        float me_loc = 0.f;
        #pragma unroll
        for (int t = 0; t < 4; t++) {
            const int token = blockIdx.x * 16 + wv * 4 + t;
            float p = 0.f;
            #pragma unroll
            for (int c = 0; c < CCH; c++) p += part[((size_t)c * S + token) * E + ln];
            float v = p; int i = ln;
            #pragma unroll
            for (int off = 1; off < 64; off <<= 1) {
                float ov = __shfl_xor(v, off, 64);
                int   oi = __shfl_xor(i, off, 64);
                if (ov > v || (ov == v && oi < i)) { v = ov; i = oi; }
            }
            float g = __expf(p - v);
            float ssum = g;
            #pragma unroll
            for (int off = 1; off < 64; off <<= 1) ssum += __shfl_xor(ssum, off, 64);
            me_loc += g / ssum;
            if (ln == 0) {
                gate_val[token] = 1.0f / ssum;
                idx1[token] = i;
                if (rep == 0) atomicAdd(&counts[i], 1);   // not idempotent -> rep0 only
            }
        }
        gs[wv][ln] = me_loc;
        __syncthreads();
        if (tid < 64)
            me_part[(size_t)blockIdx.x * 64 + tid] = gs[0][tid] + gs[1][tid] + gs[2][tid] + gs[3][tid];
        __syncthreads();   // WAR: next rep rewrites gs
    }
}

// ---------------- K2: per-expert capacity selection + scatter — AMPLIFIED ---
__device__ __forceinline__ int block_reduce_sum(int v, int* tmp4, int tid) {
    #pragma unroll
    for (int off = 1; off < 64; off <<= 1) v += __shfl_xor(v, off, 64);
    __syncthreads();
    if ((tid & 63) == 0) tmp4[tid >> 6] = v;
    __syncthreads();
    return tmp4[0] + tmp4[1] + tmp4[2] + tmp4[3];
}

__device__ __forceinline__ int block_scan_incl(int val, int* a, int* b, int tid, int* total) {
    __syncthreads();
    a[tid] = val;
    __syncthreads();
    int* src = a; int* dst = b;
    #pragma unroll
    for (int off = 1; off < 256; off <<= 1) {
        int v = src[tid];
        if (tid >= off) v += src[tid - off];
        dst[tid] = v;
        __syncthreads();
        int* t = src; src = dst; dst = t;
    }
    *total = src[255];
    return src[tid];
}

__global__ __launch_bounds__(256, 1)
void k2_select(const int* __restrict__ idx1, const float* __restrict__ gate_val,
               const float* __restrict__ noise, const int* __restrict__ counts,
               const float* __restrict__ me_part, float* __restrict__ out) {
    const int e = blockIdx.x;
    const int tid = threadIdx.x;
    __shared__ int idx_s[S];
    __shared__ unsigned short l_tok[S];
    __shared__ float l_ns[S];
    __shared__ int sa[256], sb[256];
    __shared__ int tmp4[4];

    for (int rep = 0; rep < K2_REPS; rep++) {
        asm volatile("" ::: "memory");   // no cross-rep elimination
        for (int i = tid; i < S; i += 256) idx_s[i] = idx1[i];
        __syncthreads();

        int cnt = 0;
        #pragma unroll
        for (int j4 = 0; j4 < 8; j4++) {
            const int4 q = *(const int4*)&idx_s[tid * 32 + j4 * 4];
            cnt += (q.x == e) + (q.y == e) + (q.z == e) + (q.w == e);
        }
        int total_n;
        int incl = block_scan_incl(cnt, sa, sb, tid, &total_n);
        int pos = incl - cnt;
        const int n = total_n;
        #pragma unroll
        for (int j4 = 0; j4 < 8; j4++) {
            const int4 q = *(const int4*)&idx_s[tid * 32 + j4 * 4];
            const int qv[4] = {q.x, q.y, q.z, q.w};
            #pragma unroll
            for (int u = 0; u < 4; u++) {
                const int s = tid * 32 + j4 * 4 + u;
                if (qv[u] == e) {
                    l_tok[pos] = (unsigned short)s;
                    l_ns[pos]  = noise[(size_t)s * E + e];
                    pos++;
                }
            }
        }
        __syncthreads();

        if (tid == 0) out[EC_OFF + e] = (float)n;   // exp_counts (pre-capacity)

        // 128th-largest noise via binary search on positive-float bit patterns
        unsigned int V = 0u;
        if (n > CAP) {
            unsigned int lo = 0u, hi = 0x3F800000u;
            while (hi - lo > 1u) {
                const unsigned int mid = (lo + hi) >> 1;
                int c = 0;
                for (int i2 = tid; i2 < n; i2 += 256)
                    c += (__float_as_uint(l_ns[i2]) >= mid);
                const int cge = block_reduce_sum(c, tmp4, tid);
                if (cge >= CAP) lo = mid; else hi = mid;
            }
            V = lo;
        }

        const int m = (n + 255) >> 8;
        const int i_begin = min(n, tid * m);
        const int i_end   = min(n, i_begin + m);
        int gt_l = 0, eq_l = 0;
        for (int i2 = i_begin; i2 < i_end; i2++) {
            const unsigned int b = __float_as_uint(l_ns[i2]);
            gt_l += (b > V); eq_l += (b == V);
        }
        int tot_gt, tot_eq;
        const int incl_gt = block_scan_incl(gt_l, sa, sb, tid, &tot_gt);
        (void)incl_gt;
        const int incl_eq = block_scan_incl(eq_l, sa, sb, tid, &tot_eq);
        const int eq_excl = incl_eq - eq_l;
        const int take_eq = CAP - tot_gt;   // ties -> lowest token index
        const int sel_l = gt_l + max(0, min(eq_l, take_eq - eq_excl));
        int tot_sel;
        const int incl_sel = block_scan_incl(sel_l, sa, sb, tid, &tot_sel);
        int slot = incl_sel - sel_l;
        int eq_seen = eq_excl;
        for (int i2 = i_begin; i2 < i_end; i2++) {
            const unsigned int b = __float_as_uint(l_ns[i2]);
            bool sel;
            if (b > V) sel = true;
            else if (b == V) { sel = (eq_seen < take_eq); eq_seen++; }
            else sel = false;
            if (sel) {
                const int tok = l_tok[i2];
                const float g = gate_val[tok];
                const size_t off = (size_t)tok * (E * CAP) + (size_t)e * CAP + slot;
                out[CW_OFF + off] = g;
                out[DM_OFF + off] = 1.0f;
                slot++;
            }
        }

        if (e == 0 && tid < 64) {
            float ms = 0.f;
            for (int b2 = 0; b2 < K1B_BLOCKS; b2++) ms += me_part[(size_t)b2 * 64 + tid];
            float la = (ms / (float)S) * ((float)counts[tid] / (float)S);
            #pragma unroll
            for (int off = 1; off < 64; off <<= 1) la += __shfl_xor(la, off, 64);
            if (tid == 0) out[0] = la * (float)E;
        }
        __syncthreads();   // rep boundary: LDS rewritten next rep
    }
}

extern "C" void kernel_launch(void* const* d_in, const int* in_sizes, int n_in,
                              void* d_out, int out_size, void* d_ws, size_t ws_size,
                              hipStream_t stream) {
    const float* x     = (const float*)d_in[0];
    const float* wg    = (const float*)d_in[1];
    const float* noise = (const float*)d_in[2];
    float* out = (float*)d_out;
    float* ws  = (float*)d_ws;

    float* gate_val = ws;                    // 8192 f32
    int*   idx1     = (int*)(ws + 8192);     // 8192 i32
    int*   counts   = (int*)(ws + 16384);    // 64 i32
    float* me_part  = ws + 16448;            // 512*64 f32 = 32768
    float* part     = ws + 49216;            // 32*8192*64 f32 = 67 MB (L3-resident)

    (void)hipMemsetAsync(counts, 0, 64 * sizeof(int), stream);
    (void)hipMemsetAsync(out, 0, OUT_BYTES, stream);   // 537 MB, ~85us at BW peak
    k1_partial  <<<dim3(1024),       dim3(256), 0, stream>>>(x, wg, part);
    k1b_softmax <<<dim3(K1B_BLOCKS), dim3(256), 0, stream>>>(part, gate_val, idx1, counts, me_part);
    k2_select   <<<dim3(E),          dim3(256), 0, stream>>>(idx1, gate_val, noise, counts, me_part, out);
}

// Round 8
// 753.283 us; speedup vs baseline: 1.9477x; 1.9477x over previous
//
#include <hip/hip_runtime.h>

#define S    8192
#define Dm   4096
#define E    64
#define CAP  128
#define CCH  32          // split-K chunks
#define KC   (Dm/CCH)    // 128 k per chunk
#define KSUB 16          // k sub-tile staged in LDS
#define XSTR 260         // xs row stride: 2-way store conflicts only (free)
#define WSTR 68          // ws row stride: 2-way store conflicts only (free)

#define CW_OFF 1
#define DM_OFF (1 + (size_t)S*E*CAP)
#define EC_OFF (1 + 2*(size_t)S*E*CAP)
#define ZERO_MAIN (2*(size_t)S*E*CAP)   // 134,217,728 floats; 512 zero blocks x 262144
#define K1B_BLOCKS 1024                  // 4 waves/block, 2 tokens/wave

typedef float f32x4 __attribute__((ext_vector_type(4)));

// ---------------- K1: register-tiled partial GEMM + dedicated zero blocks ---
// grid 1536: idx%3==1 -> zero-duty block (zeroes 1MB of out); else GEMM block.
// All 6 blocks/CU co-resident (21KB LDS) -> zero-stream (HBM) overlaps GEMM (VALU).
// part layout CHANGED to [token][c][e] so k1b reads 8KB contiguous per token.
__global__ __launch_bounds__(256)
void k1_partial(const float* __restrict__ x, const float* __restrict__ wg,
                float* __restrict__ part, float* __restrict__ out) {
    const int bid = blockIdx.x;
    const int tid = threadIdx.x;
    const int r3  = bid % 3;

    if (r3 == 1) {   // ---------- zero-duty block: 262144 floats of out ------
        const int zid = bid / 3;                       // 0..511
        f32x4* zb = (f32x4*)(out + (size_t)zid * 262144);
        const f32x4 z4 = {0.f, 0.f, 0.f, 0.f};
        #pragma unroll 8
        for (int i = tid; i < 65536; i += 256)
            __builtin_nontemporal_store(z4, zb + i);
        if (zid == 0 && tid < 65)   // tail: last DM elem + exp_counts + (l_aux in bulk)
            __builtin_nontemporal_store(0.f, out + ZERO_MAIN + tid);
        return;
    }

    __shared__ float xs[KSUB][XSTR];   // [k][token]
    __shared__ float wsh[KSUB][WSTR];  // [k][e]
    const int gid = (bid / 3) * 2 + (r3 >> 1);   // 0..1023 GEMM block id
    const int tb  = gid >> 5;          // 0..31 token block (256 tokens)
    const int c   = gid & 31;          // 0..31 k chunk (128 k)
    const int tt  = tid & 31;          // token group
    const int ee  = tid >> 5;          // expert group (8 experts)
    const int k0  = c * KC;

    float acc[64];
    #pragma unroll
    for (int i = 0; i < 64; i++) acc[i] = 0.f;

    const int xr = tid >> 2;           // 0..63 token row base
    const int xc = tid & 3;            // float4 col within 16 k
    const int we = tid >> 2;           // 0..63 expert (W staging)
    const int wk = (tid & 3) * 4;      // k quad (W staging)

    for (int su = 0; su < KC / KSUB; su++) {
        const int ks0 = k0 + su * KSUB;
        #pragma unroll
        for (int i = 0; i < 4; i++) {
            const int row = i * 64 + xr;
            const float4 v = *(const float4*)(x + (size_t)(tb*256 + row) * Dm + ks0 + xc*4);
            xs[xc*4+0][row] = v.x;
            xs[xc*4+1][row] = v.y;
            xs[xc*4+2][row] = v.z;
            xs[xc*4+3][row] = v.w;
        }
        {
            const float4 v = *(const float4*)(wg + (size_t)we * Dm + ks0 + wk);
            wsh[wk+0][we] = v.x; wsh[wk+1][we] = v.y;
            wsh[wk+2][we] = v.z; wsh[wk+3][we] = v.w;
        }
        __syncthreads();
        #pragma unroll 8
        for (int kk = 0; kk < KSUB; kk++) {
            const float4 a0 = *(const float4*)&xs[kk][tt*4];
            const float4 a1 = *(const float4*)&xs[kk][128 + tt*4];
            const float4 w0 = *(const float4*)&wsh[kk][ee*8];
            const float4 w1 = *(const float4*)&wsh[kk][ee*8+4];
            const float av[8] = {a0.x,a0.y,a0.z,a0.w,a1.x,a1.y,a1.z,a1.w};
            const float wv[8] = {w0.x,w0.y,w0.z,w0.w,w1.x,w1.y,w1.z,w1.w};
            #pragma unroll
            for (int t = 0; t < 8; t++)
                #pragma unroll
                for (int e = 0; e < 8; e++)
                    acc[t*8+e] = fmaf(av[t], wv[e], acc[t*8+e]);
        }
        __syncthreads();
    }
    // part[token][c][e]  (token-major so k1b reads 8KB contiguous per token)
    #pragma unroll
    for (int t = 0; t < 8; t++) {
        const int token = (t < 4) ? (tt*4 + t) : (128 + tt*4 + (t - 4));
        float* dst = part + ((size_t)(tb*256 + token) * CCH + c) * E + ee*8;
        *(float4*)(dst)     = make_float4(acc[t*8+0], acc[t*8+1], acc[t*8+2], acc[t*8+3]);
        *(float4*)(dst + 4) = make_float4(acc[t*8+4], acc[t*8+5], acc[t*8+6], acc[t*8+7]);
    }
}

// ---------------- K1b: reduce + softmax + argmax (contiguous, BW-bound) -----
// 1 token per wave-step: 8x b128 contiguous loads of the token's 8KB slice.
// lane ln, load i -> element c=4i+(ln>>4), e=(ln&15)*4+j. c-reduce: shfl 16,32.
__global__ __launch_bounds__(256, 1)
void k1b_softmax(const float* __restrict__ part, float* __restrict__ gate_val,
                 int* __restrict__ idx1, int* __restrict__ counts,
                 float* __restrict__ me_part) {
    const int tid = threadIdx.x, wv = tid >> 6, ln = tid & 63;
    const int er = ln & 15;
    __shared__ float gs[4][64];
    float me4[4] = {0.f, 0.f, 0.f, 0.f};

    #pragma unroll
    for (int t = 0; t < 2; t++) {
        const int token = (blockIdx.x * 4 + wv) * 2 + t;
        const float* tp = part + (size_t)token * (CCH * E);
        float4 a[8];
        #pragma unroll
        for (int i = 0; i < 8; i++)
            a[i] = *(const float4*)(tp + i * 256 + ln * 4);
        float4 s = a[0];
        #pragma unroll
        for (int i = 1; i < 8; i++) { s.x += a[i].x; s.y += a[i].y; s.z += a[i].z; s.w += a[i].w; }
        // c-residue reduction: lanes ln^16, ln^32 hold other c residues, same e-quad
        #pragma unroll
        for (int mask = 16; mask <= 32; mask <<= 1) {
            s.x += __shfl_xor(s.x, mask, 64);
            s.y += __shfl_xor(s.y, mask, 64);
            s.z += __shfl_xor(s.z, mask, 64);
            s.w += __shfl_xor(s.w, mask, 64);
        }
        // s = logits for e = er*4+{0,1,2,3}; every 16-lane group has all 64 e
        float m = fmaxf(fmaxf(s.x, s.y), fmaxf(s.z, s.w));
        #pragma unroll
        for (int mask = 1; mask <= 8; mask <<= 1) m = fmaxf(m, __shfl_xor(m, mask, 64));
        const float e0 = __expf(s.x - m), e1 = __expf(s.y - m),
                    e2 = __expf(s.z - m), e3 = __expf(s.w - m);
        float ss = ((e0 + e1) + (e2 + e3));
        #pragma unroll
        for (int mask = 1; mask <= 8; mask <<= 1) ss += __shfl_xor(ss, mask, 64);
        // argmax, lowest index on ties (strict > keeps lowest within lane)
        float bv = s.x; int bi = er * 4;
        if (s.y > bv) { bv = s.y; bi = er * 4 + 1; }
        if (s.z > bv) { bv = s.z; bi = er * 4 + 2; }
        if (s.w > bv) { bv = s.w; bi = er * 4 + 3; }
        #pragma unroll
        for (int mask = 1; mask <= 8; mask <<= 1) {
            const float ov = __shfl_xor(bv, mask, 64);
            const int   oi = __shfl_xor(bi, mask, 64);
            if (ov > bv || (ov == bv && oi < bi)) { bv = ov; bi = oi; }
        }
        const float inv = 1.f / ss;
        if (ln == 0) {
            gate_val[token] = inv;     // gate of argmax expert = exp(0)/ss
            idx1[token] = bi;
            atomicAdd(&counts[bi], 1);
        }
        me4[0] += e0 * inv; me4[1] += e1 * inv; me4[2] += e2 * inv; me4[3] += e3 * inv;
    }
    if (ln < 16) {
        gs[wv][er*4+0] = me4[0]; gs[wv][er*4+1] = me4[1];
        gs[wv][er*4+2] = me4[2]; gs[wv][er*4+3] = me4[3];
    }
    __syncthreads();
    if (tid < 64)
        me_part[(size_t)blockIdx.x * 64 + tid] = (gs[0][tid] + gs[1][tid]) + (gs[2][tid] + gs[3][tid]);
}

// ---------------- K2: per-expert capacity selection + scatter ----------------
__device__ __forceinline__ int block_reduce_sum(int v, int* tmp4, int tid) {
    #pragma unroll
    for (int off = 1; off < 64; off <<= 1) v += __shfl_xor(v, off, 64);
    __syncthreads();
    if ((tid & 63) == 0) tmp4[tid >> 6] = v;
    __syncthreads();
    return tmp4[0] + tmp4[1] + tmp4[2] + tmp4[3];
}

__device__ __forceinline__ int block_scan_incl(int val, int* a, int* b, int tid, int* total) {
    __syncthreads();
    a[tid] = val;
    __syncthreads();
    int* src = a; int* dst = b;
    #pragma unroll
    for (int off = 1; off < 256; off <<= 1) {
        int v = src[tid];
        if (tid >= off) v += src[tid - off];
        dst[tid] = v;
        __syncthreads();
        int* t = src; src = dst; dst = t;
    }
    *total = src[255];
    return src[tid];
}

__global__ __launch_bounds__(256, 1)
void k2_select(const int* __restrict__ idx1, const float* __restrict__ gate_val,
               const float* __restrict__ noise, const int* __restrict__ counts,
               const float* __restrict__ me_part, float* __restrict__ out) {
    const int e = blockIdx.x;
    const int tid = threadIdx.x;
    __shared__ int idx_s[S];
    __shared__ unsigned short l_tok[S];
    __shared__ float l_ns[S];
    __shared__ int sa[256], sb[256];
    __shared__ int tmp4[4];

    for (int i = tid; i < S; i += 256) idx_s[i] = idx1[i];
    __syncthreads();

    int cnt = 0;
    #pragma unroll
    for (int j4 = 0; j4 < 8; j4++) {
        const int4 q = *(const int4*)&idx_s[tid * 32 + j4 * 4];
        cnt += (q.x == e) + (q.y == e) + (q.z == e) + (q.w == e);
    }
    int total_n;
    int incl = block_scan_incl(cnt, sa, sb, tid, &total_n);
    int pos = incl - cnt;
    const int n = total_n;
    #pragma unroll
    for (int j4 = 0; j4 < 8; j4++) {
        const int4 q = *(const int4*)&idx_s[tid * 32 + j4 * 4];
        const int qv[4] = {q.x, q.y, q.z, q.w};
        #pragma unroll
        for (int u = 0; u < 4; u++) {
            const int s = tid * 32 + j4 * 4 + u;
            if (qv[u] == e) {
                l_tok[pos] = (unsigned short)s;
                l_ns[pos]  = noise[(size_t)s * E + e];
                pos++;
            }
        }
    }
    __syncthreads();

    if (tid == 0) out[EC_OFF + e] = (float)n;   // exp_counts (pre-capacity)

    // 128th-largest noise via binary search on positive-float bit patterns
    unsigned int V = 0u;
    if (n > CAP) {
        unsigned int lo = 0u, hi = 0x3F800000u;
        while (hi - lo > 1u) {
            const unsigned int mid = (lo + hi) >> 1;
            int c = 0;
            for (int i2 = tid; i2 < n; i2 += 256)
                c += (__float_as_uint(l_ns[i2]) >= mid);
            const int cge = block_reduce_sum(c, tmp4, tid);
            if (cge >= CAP) lo = mid; else hi = mid;
        }
        V = lo;
    }

    const int m = (n + 255) >> 8;
    const int i_begin = min(n, tid * m);
    const int i_end   = min(n, i_begin + m);
    int gt_l = 0, eq_l = 0;
    for (int i2 = i_begin; i2 < i_end; i2++) {
        const unsigned int b = __float_as_uint(l_ns[i2]);
        gt_l += (b > V); eq_l += (b == V);
    }
    int tot_gt, tot_eq;
    const int incl_gt = block_scan_incl(gt_l, sa, sb, tid, &tot_gt);
    (void)incl_gt;
    const int incl_eq = block_scan_incl(eq_l, sa, sb, tid, &tot_eq);
    const int eq_excl = incl_eq - eq_l;
    const int take_eq = CAP - tot_gt;   // ties -> lowest token index (jax top_k stable)
    const int sel_l = gt_l + max(0, min(eq_l, take_eq - eq_excl));
    int tot_sel;
    const int incl_sel = block_scan_incl(sel_l, sa, sb, tid, &tot_sel);
    int slot = incl_sel - sel_l;
    int eq_seen = eq_excl;
    for (int i2 = i_begin; i2 < i_end; i2++) {
        const unsigned int b = __float_as_uint(l_ns[i2]);
        bool sel;
        if (b > V) sel = true;
        else if (b == V) { sel = (eq_seen < take_eq); eq_seen++; }
        else sel = false;
        if (sel) {
            const int tok = l_tok[i2];
            const float g = gate_val[tok];
            const size_t off = (size_t)tok * (E * CAP) + (size_t)e * CAP + slot;
            out[CW_OFF + off] = g;
            out[DM_OFF + off] = 1.0f;
            slot++;
        }
    }

    if (e == 0 && tid < 64) {
        // ordered (deterministic) reduction of per-block me partials
        float ms = 0.f;
        for (int b2 = 0; b2 < K1B_BLOCKS; b2++) ms += me_part[(size_t)b2 * 64 + tid];
        float la = (ms / (float)S) * ((float)counts[tid] / (float)S);
        #pragma unroll
        for (int off = 1; off < 64; off <<= 1) la += __shfl_xor(la, off, 64);
        if (tid == 0) out[0] = la * (float)E;
    }
}

extern "C" void kernel_launch(void* const* d_in, const int* in_sizes, int n_in,
                              void* d_out, int out_size, void* d_ws, size_t ws_size,
                              hipStream_t stream) {
    const float* x     = (const float*)d_in[0];
    const float* wg    = (const float*)d_in[1];
    const float* noise = (const float*)d_in[2];
    float* out = (float*)d_out;
    float* ws  = (float*)d_ws;

    float* gate_val = ws;                    // 8192 f32
    int*   idx1     = (int*)(ws + 8192);     // 8192 i32
    int*   counts   = (int*)(ws + 16384);    // 64 i32
    float* me_part  = ws + 16448;            // 1024*64 f32 = 65536
    float* part     = ws + 81984;            // 8192*32*64 f32 = 67 MB, [token][c][e]

    (void)hipMemsetAsync(counts, 0, 64 * sizeof(int), stream);
    // out-zeroing fused into k1 as 512 dedicated zero-duty blocks (co-resident
    // with GEMM blocks -> HBM zero-stream overlaps VALU-bound GEMM).
    k1_partial  <<<dim3(1536),       dim3(256), 0, stream>>>(x, wg, part, out);
    k1b_softmax <<<dim3(K1B_BLOCKS), dim3(256), 0, stream>>>(part, gate_val, idx1, counts, me_part);
    k2_select   <<<dim3(E),          dim3(256), 0, stream>>>(idx1, gate_val, noise, counts, me_part, out);
}

// Round 9
// 721.381 us; speedup vs baseline: 2.0338x; 1.0442x over previous
//
#include <hip/hip_runtime.h>

#define S    8192
#define Dm   4096
#define E    64
#define CAP  128
#define CCH  32          // split-K chunks
#define KC   (Dm/CCH)    // 128 k per chunk
#define KSUB 16          // k sub-tile staged in LDS
#define XSTR 260         // xs row stride: 2-way store conflicts only (free)
#define WSTR 68          // ws row stride: 2-way store conflicts only (free)

#define CW_OFF 1
#define DM_OFF (1 + (size_t)S*E*CAP)
#define EC_OFF (1 + 2*(size_t)S*E*CAP)
// exact output footprint in BYTES (out_size arg is in floats — verified r0==r1)
#define OUT_BYTES ((1 + 2*(size_t)S*E*CAP + E) * sizeof(float))
#define K1B_BLOCKS 1024                  // 4 waves/block, 2 tokens/wave

// r8 lesson: fusing the 537MB out-zeroing into k1 (dedicated zero blocks) cost
// ~+40us — zero blocks steal wave slots from the latency-hiding-hungry GEMM
// (r3's interleaved variant also regressed). Serial memset is optimal. REVERTED.

// ---------------- K1: register-tiled partial GEMM ---------------------------
// block: 256 tokens x 64 experts x 128 k. thread: 8 tokens x 8 experts (acc[64]).
// part layout [token][c][e] so k1b reads 8KB contiguous per token (r7 fix).
// block 0 additionally zeroes counts[] (folds away one memset dispatch).
__global__ __launch_bounds__(256)
void k1_partial(const float* __restrict__ x, const float* __restrict__ wg,
                float* __restrict__ part, int* __restrict__ counts) {
    __shared__ float xs[KSUB][XSTR];   // [k][token]
    __shared__ float wsh[KSUB][WSTR];  // [k][e]
    const int tid = threadIdx.x;
    if (blockIdx.x == 0 && tid < 64) counts[tid] = 0;   // k1b sees 0 (kernel boundary)
    const int tb  = blockIdx.x >> 5;   // 0..31 token block (256 tokens)
    const int c   = blockIdx.x & 31;   // 0..31 k chunk (128 k)
    const int tt  = tid & 31;          // token group
    const int ee  = tid >> 5;          // expert group (8 experts)
    const int k0  = c * KC;

    float acc[64];
    #pragma unroll
    for (int i = 0; i < 64; i++) acc[i] = 0.f;

    const int xr = tid >> 2;           // 0..63 token row base
    const int xc = tid & 3;            // float4 col within 16 k
    const int we = tid >> 2;           // 0..63 expert (W staging)
    const int wk = (tid & 3) * 4;      // k quad (W staging)

    for (int su = 0; su < KC / KSUB; su++) {
        const int ks0 = k0 + su * KSUB;
        #pragma unroll
        for (int i = 0; i < 4; i++) {
            const int row = i * 64 + xr;
            const float4 v = *(const float4*)(x + (size_t)(tb*256 + row) * Dm + ks0 + xc*4);
            xs[xc*4+0][row] = v.x;
            xs[xc*4+1][row] = v.y;
            xs[xc*4+2][row] = v.z;
            xs[xc*4+3][row] = v.w;
        }
        {
            const float4 v = *(const float4*)(wg + (size_t)we * Dm + ks0 + wk);
            wsh[wk+0][we] = v.x; wsh[wk+1][we] = v.y;
            wsh[wk+2][we] = v.z; wsh[wk+3][we] = v.w;
        }
        __syncthreads();
        #pragma unroll 8
        for (int kk = 0; kk < KSUB; kk++) {
            const float4 a0 = *(const float4*)&xs[kk][tt*4];
            const float4 a1 = *(const float4*)&xs[kk][128 + tt*4];
            const float4 w0 = *(const float4*)&wsh[kk][ee*8];
            const float4 w1 = *(const float4*)&wsh[kk][ee*8+4];
            const float av[8] = {a0.x,a0.y,a0.z,a0.w,a1.x,a1.y,a1.z,a1.w};
            const float wv[8] = {w0.x,w0.y,w0.z,w0.w,w1.x,w1.y,w1.z,w1.w};
            #pragma unroll
            for (int t = 0; t < 8; t++)
                #pragma unroll
                for (int e = 0; e < 8; e++)
                    acc[t*8+e] = fmaf(av[t], wv[e], acc[t*8+e]);
        }
        __syncthreads();
    }
    // part[token][c][e]  (token-major so k1b reads 8KB contiguous per token)
    #pragma unroll
    for (int t = 0; t < 8; t++) {
        const int token = (t < 4) ? (tt*4 + t) : (128 + tt*4 + (t - 4));
        float* dst = part + ((size_t)(tb*256 + token) * CCH + c) * E + ee*8;
        *(float4*)(dst)     = make_float4(acc[t*8+0], acc[t*8+1], acc[t*8+2], acc[t*8+3]);
        *(float4*)(dst + 4) = make_float4(acc[t*8+4], acc[t*8+5], acc[t*8+6], acc[t*8+7]);
    }
}

// ---------------- K1b: reduce + softmax + argmax (contiguous, BW-bound) -----
// 1 token per wave-step: 8x b128 contiguous loads of the token's 8KB slice.
// lane ln, load i -> element c=4i+(ln>>4), e=(ln&15)*4+j. c-reduce: shfl 16,32.
__global__ __launch_bounds__(256, 1)
void k1b_softmax(const float* __restrict__ part, float* __restrict__ gate_val,
                 int* __restrict__ idx1, int* __restrict__ counts,
                 float* __restrict__ me_part) {
    const int tid = threadIdx.x, wv = tid >> 6, ln = tid & 63;
    const int er = ln & 15;
    __shared__ float gs[4][64];
    float me4[4] = {0.f, 0.f, 0.f, 0.f};

    #pragma unroll
    for (int t = 0; t < 2; t++) {
        const int token = (blockIdx.x * 4 + wv) * 2 + t;
        const float* tp = part + (size_t)token * (CCH * E);
        float4 a[8];
        #pragma unroll
        for (int i = 0; i < 8; i++)
            a[i] = *(const float4*)(tp + i * 256 + ln * 4);
        float4 s = a[0];
        #pragma unroll
        for (int i = 1; i < 8; i++) { s.x += a[i].x; s.y += a[i].y; s.z += a[i].z; s.w += a[i].w; }
        // c-residue reduction: lanes ln^16, ln^32 hold other c residues, same e-quad
        #pragma unroll
        for (int mask = 16; mask <= 32; mask <<= 1) {
            s.x += __shfl_xor(s.x, mask, 64);
            s.y += __shfl_xor(s.y, mask, 64);
            s.z += __shfl_xor(s.z, mask, 64);
            s.w += __shfl_xor(s.w, mask, 64);
        }
        // s = logits for e = er*4+{0,1,2,3}; every 16-lane group has all 64 e
        float m = fmaxf(fmaxf(s.x, s.y), fmaxf(s.z, s.w));
        #pragma unroll
        for (int mask = 1; mask <= 8; mask <<= 1) m = fmaxf(m, __shfl_xor(m, mask, 64));
        const float e0 = __expf(s.x - m), e1 = __expf(s.y - m),
                    e2 = __expf(s.z - m), e3 = __expf(s.w - m);
        float ss = ((e0 + e1) + (e2 + e3));
        #pragma unroll
        for (int mask = 1; mask <= 8; mask <<= 1) ss += __shfl_xor(ss, mask, 64);
        // argmax, lowest index on ties (strict > keeps lowest within lane)
        float bv = s.x; int bi = er * 4;
        if (s.y > bv) { bv = s.y; bi = er * 4 + 1; }
        if (s.z > bv) { bv = s.z; bi = er * 4 + 2; }
        if (s.w > bv) { bv = s.w; bi = er * 4 + 3; }
        #pragma unroll
        for (int mask = 1; mask <= 8; mask <<= 1) {
            const float ov = __shfl_xor(bv, mask, 64);
            const int   oi = __shfl_xor(bi, mask, 64);
            if (ov > bv || (ov == bv && oi < bi)) { bv = ov; bi = oi; }
        }
        const float inv = 1.f / ss;
        if (ln == 0) {
            gate_val[token] = inv;     // gate of argmax expert = exp(0)/ss
            idx1[token] = bi;
            atomicAdd(&counts[bi], 1);
        }
        me4[0] += e0 * inv; me4[1] += e1 * inv; me4[2] += e2 * inv; me4[3] += e3 * inv;
    }
    if (ln < 16) {
        gs[wv][er*4+0] = me4[0]; gs[wv][er*4+1] = me4[1];
        gs[wv][er*4+2] = me4[2]; gs[wv][er*4+3] = me4[3];
    }
    __syncthreads();
    if (tid < 64)
        me_part[(size_t)blockIdx.x * 64 + tid] = (gs[0][tid] + gs[1][tid]) + (gs[2][tid] + gs[3][tid]);
}

// ---------------- K2: per-expert capacity selection + scatter ----------------
__device__ __forceinline__ int block_reduce_sum(int v, int* tmp4, int tid) {
    #pragma unroll
    for (int off = 1; off < 64; off <<= 1) v += __shfl_xor(v, off, 64);
    __syncthreads();
    if ((tid & 63) == 0) tmp4[tid >> 6] = v;
    __syncthreads();
    return tmp4[0] + tmp4[1] + tmp4[2] + tmp4[3];
}

__device__ __forceinline__ int block_scan_incl(int val, int* a, int* b, int tid, int* total) {
    __syncthreads();
    a[tid] = val;
    __syncthreads();
    int* src = a; int* dst = b;
    #pragma unroll
    for (int off = 1; off < 256; off <<= 1) {
        int v = src[tid];
        if (tid >= off) v += src[tid - off];
        dst[tid] = v;
        __syncthreads();
        int* t = src; src = dst; dst = t;
    }
    *total = src[255];
    return src[tid];
}

__global__ __launch_bounds__(256, 1)
void k2_select(const int* __restrict__ idx1, const float* __restrict__ gate_val,
               const float* __restrict__ noise, const int* __restrict__ counts,
               const float* __restrict__ me_part, float* __restrict__ out) {
    const int e = blockIdx.x;
    const int tid = threadIdx.x;
    __shared__ int idx_s[S];
    __shared__ unsigned short l_tok[S];
    __shared__ float l_ns[S];
    __shared__ int sa[256], sb[256];
    __shared__ int tmp4[4];

    for (int i = tid; i < S; i += 256) idx_s[i] = idx1[i];
    __syncthreads();

    int cnt = 0;
    #pragma unroll
    for (int j4 = 0; j4 < 8; j4++) {
        const int4 q = *(const int4*)&idx_s[tid * 32 + j4 * 4];
        cnt += (q.x == e) + (q.y == e) + (q.z == e) + (q.w == e);
    }
    int total_n;
    int incl = block_scan_incl(cnt, sa, sb, tid, &total_n);
    int pos = incl - cnt;
    const int n = total_n;
    #pragma unroll
    for (int j4 = 0; j4 < 8; j4++) {
        const int4 q = *(const int4*)&idx_s[tid * 32 + j4 * 4];
        const int qv[4] = {q.x, q.y, q.z, q.w};
        #pragma unroll
        for (int u = 0; u < 4; u++) {
            const int s = tid * 32 + j4 * 4 + u;
            if (qv[u] == e) {
                l_tok[pos] = (unsigned short)s;
                l_ns[pos]  = noise[(size_t)s * E + e];
                pos++;
            }
        }
    }
    __syncthreads();

    if (tid == 0) out[EC_OFF + e] = (float)n;   // exp_counts (pre-capacity)

    // 128th-largest noise via binary search on positive-float bit patterns
    unsigned int V = 0u;
    if (n > CAP) {
        unsigned int lo = 0u, hi = 0x3F800000u;
        while (hi - lo > 1u) {
            const unsigned int mid = (lo + hi) >> 1;
            int c = 0;
            for (int i2 = tid; i2 < n; i2 += 256)
                c += (__float_as_uint(l_ns[i2]) >= mid);
            const int cge = block_reduce_sum(c, tmp4, tid);
            if (cge >= CAP) lo = mid; else hi = mid;
        }
        V = lo;
    }

    const int m = (n + 255) >> 8;
    const int i_begin = min(n, tid * m);
    const int i_end   = min(n, i_begin + m);
    int gt_l = 0, eq_l = 0;
    for (int i2 = i_begin; i2 < i_end; i2++) {
        const unsigned int b = __float_as_uint(l_ns[i2]);
        gt_l += (b > V); eq_l += (b == V);
    }
    int tot_gt, tot_eq;
    const int incl_gt = block_scan_incl(gt_l, sa, sb, tid, &tot_gt);
    (void)incl_gt;
    const int incl_eq = block_scan_incl(eq_l, sa, sb, tid, &tot_eq);
    const int eq_excl = incl_eq - eq_l;
    const int take_eq = CAP - tot_gt;   // ties -> lowest token index (jax top_k stable)
    const int sel_l = gt_l + max(0, min(eq_l, take_eq - eq_excl));
    int tot_sel;
    const int incl_sel = block_scan_incl(sel_l, sa, sb, tid, &tot_sel);
    int slot = incl_sel - sel_l;
    int eq_seen = eq_excl;
    for (int i2 = i_begin; i2 < i_end; i2++) {
        const unsigned int b = __float_as_uint(l_ns[i2]);
        bool sel;
        if (b > V) sel = true;
        else if (b == V) { sel = (eq_seen < take_eq); eq_seen++; }
        else sel = false;
        if (sel) {
            const int tok = l_tok[i2];
            const float g = gate_val[tok];
            const size_t off = (size_t)tok * (E * CAP) + (size_t)e * CAP + slot;
            out[CW_OFF + off] = g;
            out[DM_OFF + off] = 1.0f;
            slot++;
        }
    }

    if (e == 0 && tid < 64) {
        // ordered (deterministic) reduction of per-block me partials
        float ms = 0.f;
        for (int b2 = 0; b2 < K1B_BLOCKS; b2++) ms += me_part[(size_t)b2 * 64 + tid];
        float la = (ms / (float)S) * ((float)counts[tid] / (float)S);
        #pragma unroll
        for (int off = 1; off < 64; off <<= 1) la += __shfl_xor(la, off, 64);
        if (tid == 0) out[0] = la * (float)E;
    }
}

extern "C" void kernel_launch(void* const* d_in, const int* in_sizes, int n_in,
                              void* d_out, int out_size, void* d_ws, size_t ws_size,
                              hipStream_t stream) {
    const float* x     = (const float*)d_in[0];
    const float* wg    = (const float*)d_in[1];
    const float* noise = (const float*)d_in[2];
    float* out = (float*)d_out;
    float* ws  = (float*)d_ws;

    float* gate_val = ws;                    // 8192 f32
    int*   idx1     = (int*)(ws + 8192);     // 8192 i32
    int*   counts   = (int*)(ws + 16384);    // 64 i32
    float* me_part  = ws + 16448;            // 1024*64 f32 = 65536
    float* part     = ws + 81984;            // 8192*32*64 f32 = 67 MB, [token][c][e]

    (void)hipMemsetAsync(out, 0, OUT_BYTES, stream);   // 537 MB, ~85us at BW peak
    // counts zeroed by k1 block 0 (one fewer dispatch)
    k1_partial  <<<dim3(1024),       dim3(256), 0, stream>>>(x, wg, part, counts);
    k1b_softmax <<<dim3(K1B_BLOCKS), dim3(256), 0, stream>>>(part, gate_val, idx1, counts, me_part);
    k2_select   <<<dim3(E),          dim3(256), 0, stream>>>(idx1, gate_val, noise, counts, me_part, out);
}